// Round 2
// baseline (145.382 us; speedup 1.0000x reference)
//
#include <hip/hip_runtime.h>

// HMM forward: alpha_t = (alpha_{t-1} @ A) * B[:, obs[t]]; out[t][s] = alpha_t[s].
// S=2048, T=8192, 512 symbols, fp32.
//
// alpha decays ~512x/step -> exact-zero underflow at t~17; after the first
// all-zero row every later row is zero (verified R1-R8, absmax 1e-38).
// Honest recurrence + all-zero detection + zero tail.
//
// R8 post-mortem (57us kernel): WRITE_SIZE=65.7MB at 1.37TB/s -- the 64MB tail
// zero-fill ran on only 64 blocks (64 CUs x ~25-40GB/s/CU = the measured BW),
// i.e. ~26-43us of the 57us. The recurrence itself is ~20-30us.
// R9: grid 64 -> 256. Blocks 64..255 are FILLERS: they zero rows [128,8192)
// immediately, fully overlapped with the recurrence (statically disjoint from
// everything the recurrence touches while t<128). Compute blocks only zero the
// residue [lastRow+1,128). Honest for arbitrary inputs: if the recurrence ever
// reaches t==128 it acquire-waits on the fillers' release done-counter before
// overwriting filler-zeroed rows (never taken for the benchmark input).
// R10: fix compile -- __builtin_nontemporal_store needs a clang ext_vector,
// not HIP's float4 class. v4f typedef for the zero-fill stores.
//
// Recurrence (unchanged from R8): A slice lives in REGISTERS -- each lane's 16
// float4 of A are step-invariant; 64 VGPR/lane x 1024 threads = the block's
// whole 256KB slice. Consumers stream producer chunks directly (wave w owns
// chunks w,w+16,w+32,w+48; each lane batch-polls its 16 encoded alpha scalars,
// 8 lanes/address coalesced broadcast), FMA vs register A, shfl-reduce, ONE
// barrier, wave0 combines and publishes. s_nz is depth-4 parity.
// Encoding: enc = bits(a)+2^30 in [0x40000000,0x7F800000] (alpha in [0,1]);
// poison 0xAA.., zeros, and stale DECODED values all read not-ready.
// Post-loop: flag rendezvous, in-place decode, residue zero-fill.

#define S     2048
#define T     8192
#define NSYM  512
#define NCBLK 64                         // compute blocks
#define NFILL 192                        // filler blocks
#define NBLK  (NCBLK + NFILL)
#define NTHR  1024
#define READY 0x40000000
#define FILL_START 128                   // rows >= this are filler-owned
#define ROWS_PER_FILL ((T - FILL_START) / NFILL)   // 8064/192 = 42 exactly

typedef int   v4i __attribute__((ext_vector_type(4)));
typedef float v4f __attribute__((ext_vector_type(4)));

__device__ __forceinline__ v4i load_coherent_i4(const int* p) {
    v4i r;
    asm volatile("global_load_dwordx4 %0, %1, off sc0 sc1\n\ts_waitcnt vmcnt(0)"
                 : "=v"(r) : "v"(p) : "memory");
    return r;
}
__device__ __forceinline__ void store_coherent_i4(int* p, v4i v) {
    asm volatile("global_store_dwordx4 %0, %1, off sc0 sc1"
                 :: "v"(p), "v"(v) : "memory");
}

// 4 coherent scalar loads from one base (+0,+32,+64,+96 bytes), NO waitcnt.
#define POLL4(e0,e1,e2,e3,bp)                                              \
    asm volatile("global_load_dword %0, %4, off sc0 sc1\n\t"               \
                 "global_load_dword %1, %4, off offset:32 sc0 sc1\n\t"     \
                 "global_load_dword %2, %4, off offset:64 sc0 sc1\n\t"     \
                 "global_load_dword %3, %4, off offset:96 sc0 sc1"         \
                 : "=&v"(e0), "=&v"(e1), "=&v"(e2), "=&v"(e3)              \
                 : "v"(bp) : "memory")

__global__ void __launch_bounds__(NTHR) hmm_fwd(
    const int*   __restrict__ obs,
    const float* __restrict__ A,
    const float* __restrict__ B,
    const float* __restrict__ pi,
    float*       __restrict__ out,
    unsigned*    __restrict__ flag)      // [0..63]: rendezvous; [64]: filler done-count
{
    __shared__ float4 s_wpart[16][8];    // 2 KB per-wave partials
    __shared__ int    s_nz[4];           // depth-4 parity "row nonzero"

    const int tx   = threadIdx.x;
    const int b    = blockIdx.x;

    // ---------------- filler blocks: zero rows [128, 8192) NOW ----------------
    if (b >= NCBLK) {
        const int fb = b - NCBLK;
        v4f* dst = (v4f*)(out + (size_t)(FILL_START + fb * ROWS_PER_FILL) * S);
        const int n4 = ROWS_PER_FILL * (S / 4);       // 21504 = 21 * 1024
        const v4f z = {0.f, 0.f, 0.f, 0.f};
        for (int i = tx; i < n4; i += NTHR)
            __builtin_nontemporal_store(z, &dst[i]);
        __syncthreads();                              // all lanes' stores issued
        if (tx == 0) {
            __threadfence();                          // stores visible device-wide
            __hip_atomic_fetch_add(&flag[NCBLK], 1u,
                                   __ATOMIC_RELEASE, __HIP_MEMORY_SCOPE_AGENT);
        }
        return;
    }

    // ---------------- compute blocks (identical to R8 except noted) -----------
    const int lane = tx & 63;
    const int w    = tx >> 6;            // wave id 0..15
    const int jl4  = lane & 7;           // col float4 within block (0..7)
    const int r_l  = lane >> 3;          // row-within-group (0..7)
    const int col4 = b * 8 + jl4;
    const float4* A4 = (const float4*)A;

    // hoist the block's A slice into registers: a[q][s] = A4[i][col4],
    // i = (w+16q)*32 + s*8 + r_l  (step-invariant!)
    float4 a_reg[4][4];
    #pragma unroll
    for (int q = 0; q < 4; ++q)
        #pragma unroll
        for (int s = 0; s < 4; ++s) {
            const int i = (w + 16 * q) * 32 + s * 8 + r_l;
            a_reg[q][s] = A4[(size_t)i * (S / 4) + col4];
        }

    // step 0: publish encoded alpha0 chunk = pi * B[:, obs[0]]
    if (tx < 8) {
        const int o0 = obs[0];
        const int j  = b * 32 + tx * 4;
        v4i e;
        e.x = __float_as_int(pi[j + 0] * B[(size_t)(j + 0) * NSYM + o0]) + READY;
        e.y = __float_as_int(pi[j + 1] * B[(size_t)(j + 1) * NSYM + o0]) + READY;
        e.z = __float_as_int(pi[j + 2] * B[(size_t)(j + 2) * NSYM + o0]) + READY;
        e.w = __float_as_int(pi[j + 3] * B[(size_t)(j + 3) * NSYM + o0]) + READY;
        store_coherent_i4((int*)out + j, e);
    }
    if (tx == 0) { s_nz[0] = 0; s_nz[1] = 0; s_nz[2] = 0; s_nz[3] = 0; }
    __syncthreads();

    int lastRow = T - 1;

    for (int t = 1; t < T; ++t) {
        // safety gate (never taken for benchmark input): before writing any
        // filler-owned row, wait for ALL fillers; acquire pairs with their
        // release so our overwrites are ordered after their zeros.
        if (t == FILL_START) {
            if (tx == 0) {
                while (__hip_atomic_load(&flag[NCBLK], __ATOMIC_ACQUIRE,
                                         __HIP_MEMORY_SCOPE_AGENT) < NFILL)
                    __builtin_amdgcn_s_sleep(8);
            }
            __syncthreads();
        }

        // ---- emission prefetch (wave0 lanes; same lanes publish later) ----
        float em0 = 0.f, em1 = 0.f, em2 = 0.f, em3 = 0.f;
        if (tx < 8) {
            const int o = obs[t];
            const int j = b * 32 + tx * 4;
            em0 = B[(size_t)(j + 0) * NSYM + o];
            em1 = B[(size_t)(j + 1) * NSYM + o];
            em2 = B[(size_t)(j + 2) * NSYM + o];
            em3 = B[(size_t)(j + 3) * NSYM + o];
        }

        // ---- batch-poll this wave's 16 encoded alpha scalars of row t-1 ----
        const int* rb = (const int*)(out + (size_t)(t - 1) * S) + r_l;
        const int* b0 = rb + (w +  0) * 32;
        const int* b1 = rb + (w + 16) * 32;
        const int* b2 = rb + (w + 32) * 32;
        const int* b3 = rb + (w + 48) * 32;
        int e00, e01, e02, e03, e10, e11, e12, e13;
        int e20, e21, e22, e23, e30, e31, e32, e33;
        for (;;) {
            POLL4(e00, e01, e02, e03, b0);
            POLL4(e10, e11, e12, e13, b1);
            POLL4(e20, e21, e22, e23, b2);
            POLL4(e30, e31, e32, e33, b3);
            asm volatile("s_waitcnt vmcnt(0)" ::: "memory");
            const int m0 = (e00 < READY) | (e01 < READY) | (e02 < READY) | (e03 < READY);
            const int m1 = (e10 < READY) | (e11 < READY) | (e12 < READY) | (e13 < READY);
            const int m2 = (e20 < READY) | (e21 < READY) | (e22 < READY) | (e23 < READY);
            const int m3 = (e30 < READY) | (e31 < READY) | (e32 < READY) | (e33 < READY);
            if (!(m0 | m1 | m2 | m3)) break;
        }

        // ---- decode + FMA vs register-resident A ----
        float4 acc = make_float4(0.f, 0.f, 0.f, 0.f);
        int nzacc = 0;
        #define STEP1(E, Q, Ss)                                                \
            { const int d = (E) - READY; nzacc |= d;                           \
              const float af = __int_as_float(d);                              \
              acc.x = fmaf(af, a_reg[Q][Ss].x, acc.x);                         \
              acc.y = fmaf(af, a_reg[Q][Ss].y, acc.y);                         \
              acc.z = fmaf(af, a_reg[Q][Ss].z, acc.z);                         \
              acc.w = fmaf(af, a_reg[Q][Ss].w, acc.w); }
        STEP1(e00,0,0) STEP1(e01,0,1) STEP1(e02,0,2) STEP1(e03,0,3)
        STEP1(e10,1,0) STEP1(e11,1,1) STEP1(e12,1,2) STEP1(e13,1,3)
        STEP1(e20,2,0) STEP1(e21,2,1) STEP1(e22,2,2) STEP1(e23,2,3)
        STEP1(e30,3,0) STEP1(e31,3,1) STEP1(e32,3,2) STEP1(e33,3,3)
        #undef STEP1

        // in-wave reduce over lane bits 3,4,5 (the 8 r_l groups)
        #pragma unroll
        for (int m = 8; m <= 32; m <<= 1) {
            acc.x += __shfl_xor(acc.x, m);
            acc.y += __shfl_xor(acc.y, m);
            acc.z += __shfl_xor(acc.z, m);
            acc.w += __shfl_xor(acc.w, m);
        }
        if (lane < 8) s_wpart[w][lane] = acc;
        const unsigned long long nzm = __ballot(nzacc != 0);
        if (nzm != 0ull && lane == 0) s_nz[t & 3] = 1;   // benign same-value race
        if (tx == 0) s_nz[(t + 2) & 3] = 0;              // prep 2 steps ahead
        __syncthreads();                                 // the ONLY per-step barrier

        if (s_nz[t & 3] == 0) { lastRow = t - 1; break; }   // uniform everywhere

        // ---- wave0: combine 16 wave-partials, emission-multiply, publish ----
        if (tx < 64) {
            const int h = tx >> 3, c = tx & 7;
            float4 p = s_wpart[h][c];
            const float4 q4 = s_wpart[h + 8][c];
            p.x += q4.x; p.y += q4.y; p.z += q4.z; p.w += q4.w;
            #pragma unroll
            for (int m = 8; m <= 32; m <<= 1) {
                p.x += __shfl_xor(p.x, m);
                p.y += __shfl_xor(p.y, m);
                p.z += __shfl_xor(p.z, m);
                p.w += __shfl_xor(p.w, m);
            }
            if (tx < 8) {
                v4i e;
                e.x = __float_as_int(p.x * em0) + READY;
                e.y = __float_as_int(p.y * em1) + READY;
                e.z = __float_as_int(p.z * em2) + READY;
                e.w = __float_as_int(p.w * em3) + READY;
                store_coherent_i4((int*)(out + (size_t)t * S) + b * 32 + tx * 4, e);
            }
        }
        // no bottom barrier: next step's polls gate progress (R7/R8-proven).
    }

    // ---- one-time rendezvous: nobody decodes rows still being poll-read ----
    if (tx == 0)
        __hip_atomic_store(&flag[b], 1u, __ATOMIC_RELAXED, __HIP_MEMORY_SCOPE_AGENT);
    if (tx < 64) {
        for (;;) {
            const unsigned f = __hip_atomic_load(&flag[tx], __ATOMIC_RELAXED,
                                                 __HIP_MEMORY_SCOPE_AGENT);
            if (__all(f == 1u)) break;
            __builtin_amdgcn_s_sleep(1);
        }
    }
    __syncthreads();

    // ---- decode own chunks of rows 0..lastRow in place ----
    for (int idx = tx; idx < (lastRow + 1) * 8; idx += NTHR) {
        const int r = idx >> 3, c = idx & 7;
        int* p = (int*)(out + (size_t)r * S) + b * 32 + c * 4;
        v4i e = load_coherent_i4(p);
        e.x -= READY; e.y -= READY; e.z -= READY; e.w -= READY;
        store_coherent_i4(p, e);
    }

    // ---- residue zero-fill: rows lastRow+1 .. FILL_START-1 (fillers own the rest)
    {
        const int zbeg = lastRow + 1;
        const int zend = (FILL_START > zbeg) ? FILL_START : zbeg;
        const size_t beg4 = (size_t)zbeg * (S / 4);
        const size_t end4 = (size_t)zend * (S / 4);
        const v4f z = {0.f, 0.f, 0.f, 0.f};
        v4f* o4 = (v4f*)out;
        for (size_t i = beg4 + (size_t)b * NTHR + tx; i < end4;
             i += (size_t)NCBLK * NTHR)
            __builtin_nontemporal_store(z, &o4[i]);
    }
}

extern "C" void kernel_launch(void* const* d_in, const int* in_sizes, int n_in,
                              void* d_out, int out_size, void* d_ws, size_t ws_size,
                              hipStream_t stream) {
    const int*   obs = (const int*)d_in[0];
    const float* A   = (const float*)d_in[1];
    const float* B   = (const float*)d_in[2];
    const float* pi  = (const float*)d_in[3];
    float* out = (float*)d_out;
    unsigned* flag = (unsigned*)d_ws;

    // d_ws is poisoned before every launch; rendezvous flags + filler
    // done-counter must start at 0.
    (void)hipMemsetAsync(d_ws, 0, (size_t)(NCBLK + 1) * sizeof(unsigned), stream);

    hmm_fwd<<<dim3(NBLK), dim3(NTHR), 0, stream>>>(obs, A, B, pi, out, flag);
}

// Round 4
// 142.897 us; speedup vs baseline: 1.0174x; 1.0174x over previous
//
#include <hip/hip_runtime.h>

// HMM forward: alpha_t = (alpha_{t-1} @ A) * B[:, obs[t]]; out[t][s] = alpha_t[s].
// S=2048, T=8192, 512 symbols, fp32.
//
// alpha decays ~512x/step -> exact-zero underflow at t~17; after the first
// all-zero row every later row is zero (verified R1-R10, absmax 1e-38).
// Honest recurrence + all-zero detection + zero tail.
//
// R10 post-mortem (73us, WORSE than R8's 57us): running the 64MB fill
// concurrently with the recurrence made BOTH slow -- the poll loop's
// device-scope load storm and the fill's write stream share L2/L3/fabric;
// avg BW dropped 1.37->1.05 TB/s. Overlap is wrong when one side is a
// latency-bound serial chain.
// R11: keep the WIDE fill (192 filler blocks, ~5-6 TB/s) but SERIALIZE it
// behind the recurrence. Fillers sleep-poll a go-flag (1 lane, s_sleep(32)
// cadence -- negligible traffic) until compute blocks signal recurrence-done,
// then stream rows [128,8192). Compute blocks zero the residue
// [lastRow+1,128). Deadlock-free for arbitrary inputs: a compute block
// reaching t==FILL_START sets the go-flag BEFORE acquire-waiting on the
// fillers' done-counter.
// R12: identical resubmit of R11 -- the R11 round died to an infra failure
// ("MI355X container failed twice") with no kernel data. Hang audit clean:
// compute blocks dispatch first; fillers only sleep; go-flag is set
// unconditionally post-loop; gate sets go before waiting.
//
// Recurrence (unchanged from R8): A slice lives in REGISTERS -- each lane's 16
// float4 of A are step-invariant; 64 VGPR/lane x 1024 threads = the block's
// whole 256KB slice. Consumers stream producer chunks directly (wave w owns
// chunks w,w+16,w+32,w+48; each lane batch-polls its 16 encoded alpha scalars,
// 8 lanes/address coalesced broadcast), FMA vs register A, shfl-reduce, ONE
// barrier, wave0 combines and publishes. s_nz is depth-4 parity.
// Encoding: enc = bits(a)+2^30 in [0x40000000,0x7F800000] (alpha in [0,1]);
// poison 0xAA.., zeros, and stale DECODED values all read not-ready.
// Post-loop: flag rendezvous, in-place decode, residue zero-fill.
//
// flag[] layout (d_ws): [0..63] per-block rendezvous; [64] filler done-count
// (release/acquire); [65] go-flag for fillers (relaxed).

#define S     2048
#define T     8192
#define NSYM  512
#define NCBLK 64                         // compute blocks
#define NFILL 192                        // filler blocks
#define NBLK  (NCBLK + NFILL)
#define NTHR  1024
#define READY 0x40000000
#define FILL_START 128                   // rows >= this are filler-owned
#define ROWS_PER_FILL ((T - FILL_START) / NFILL)   // 8064/192 = 42 exactly

typedef int   v4i __attribute__((ext_vector_type(4)));
typedef float v4f __attribute__((ext_vector_type(4)));

__device__ __forceinline__ v4i load_coherent_i4(const int* p) {
    v4i r;
    asm volatile("global_load_dwordx4 %0, %1, off sc0 sc1\n\ts_waitcnt vmcnt(0)"
                 : "=v"(r) : "v"(p) : "memory");
    return r;
}
__device__ __forceinline__ void store_coherent_i4(int* p, v4i v) {
    asm volatile("global_store_dwordx4 %0, %1, off sc0 sc1"
                 :: "v"(p), "v"(v) : "memory");
}

// 4 coherent scalar loads from one base (+0,+32,+64,+96 bytes), NO waitcnt.
#define POLL4(e0,e1,e2,e3,bp)                                              \
    asm volatile("global_load_dword %0, %4, off sc0 sc1\n\t"               \
                 "global_load_dword %1, %4, off offset:32 sc0 sc1\n\t"     \
                 "global_load_dword %2, %4, off offset:64 sc0 sc1\n\t"     \
                 "global_load_dword %3, %4, off offset:96 sc0 sc1"         \
                 : "=&v"(e0), "=&v"(e1), "=&v"(e2), "=&v"(e3)              \
                 : "v"(bp) : "memory")

__global__ void __launch_bounds__(NTHR) hmm_fwd(
    const int*   __restrict__ obs,
    const float* __restrict__ A,
    const float* __restrict__ B,
    const float* __restrict__ pi,
    float*       __restrict__ out,
    unsigned*    __restrict__ flag)
{
    __shared__ float4 s_wpart[16][8];    // 2 KB per-wave partials
    __shared__ int    s_nz[4];           // depth-4 parity "row nonzero"

    const int tx   = threadIdx.x;
    const int b    = blockIdx.x;

    // ----- filler blocks: WAIT for recurrence-done, then zero rows [128,8192) -----
    if (b >= NCBLK) {
        if (tx == 0) {
            while (__hip_atomic_load(&flag[NCBLK + 1], __ATOMIC_RELAXED,
                                     __HIP_MEMORY_SCOPE_AGENT) == 0u)
                __builtin_amdgcn_s_sleep(32);      // ~0.85us cadence, 1 lane
        }
        __syncthreads();
        const int fb = b - NCBLK;
        v4f* dst = (v4f*)(out + (size_t)(FILL_START + fb * ROWS_PER_FILL) * S);
        const int n4 = ROWS_PER_FILL * (S / 4);       // 21504 = 21 * 1024
        const v4f z = {0.f, 0.f, 0.f, 0.f};
        for (int i = tx; i < n4; i += NTHR)
            __builtin_nontemporal_store(z, &dst[i]);
        __syncthreads();                              // all lanes' stores issued
        if (tx == 0) {
            __threadfence();                          // stores visible device-wide
            __hip_atomic_fetch_add(&flag[NCBLK], 1u,
                                   __ATOMIC_RELEASE, __HIP_MEMORY_SCOPE_AGENT);
        }
        return;
    }

    // ---------------- compute blocks (recurrence identical to R8) -------------
    const int lane = tx & 63;
    const int w    = tx >> 6;            // wave id 0..15
    const int jl4  = lane & 7;           // col float4 within block (0..7)
    const int r_l  = lane >> 3;          // row-within-group (0..7)
    const int col4 = b * 8 + jl4;
    const float4* A4 = (const float4*)A;

    // hoist the block's A slice into registers: a[q][s] = A4[i][col4],
    // i = (w+16q)*32 + s*8 + r_l  (step-invariant!)
    float4 a_reg[4][4];
    #pragma unroll
    for (int q = 0; q < 4; ++q)
        #pragma unroll
        for (int s = 0; s < 4; ++s) {
            const int i = (w + 16 * q) * 32 + s * 8 + r_l;
            a_reg[q][s] = A4[(size_t)i * (S / 4) + col4];
        }

    // step 0: publish encoded alpha0 chunk = pi * B[:, obs[0]]
    if (tx < 8) {
        const int o0 = obs[0];
        const int j  = b * 32 + tx * 4;
        v4i e;
        e.x = __float_as_int(pi[j + 0] * B[(size_t)(j + 0) * NSYM + o0]) + READY;
        e.y = __float_as_int(pi[j + 1] * B[(size_t)(j + 1) * NSYM + o0]) + READY;
        e.z = __float_as_int(pi[j + 2] * B[(size_t)(j + 2) * NSYM + o0]) + READY;
        e.w = __float_as_int(pi[j + 3] * B[(size_t)(j + 3) * NSYM + o0]) + READY;
        store_coherent_i4((int*)out + j, e);
    }
    if (tx == 0) { s_nz[0] = 0; s_nz[1] = 0; s_nz[2] = 0; s_nz[3] = 0; }
    __syncthreads();

    int lastRow = T - 1;

    for (int t = 1; t < T; ++t) {
        // safety gate (never taken for benchmark input): before writing any
        // filler-owned row, release the fillers (go-flag FIRST -- deadlock-free)
        // then acquire-wait for their zeros to be globally visible.
        if (t == FILL_START) {
            if (tx == 0) {
                __hip_atomic_store(&flag[NCBLK + 1], 1u, __ATOMIC_RELAXED,
                                   __HIP_MEMORY_SCOPE_AGENT);
                while (__hip_atomic_load(&flag[NCBLK], __ATOMIC_ACQUIRE,
                                         __HIP_MEMORY_SCOPE_AGENT) < NFILL)
                    __builtin_amdgcn_s_sleep(8);
            }
            __syncthreads();
        }

        // ---- emission prefetch (wave0 lanes; same lanes publish later) ----
        float em0 = 0.f, em1 = 0.f, em2 = 0.f, em3 = 0.f;
        if (tx < 8) {
            const int o = obs[t];
            const int j = b * 32 + tx * 4;
            em0 = B[(size_t)(j + 0) * NSYM + o];
            em1 = B[(size_t)(j + 1) * NSYM + o];
            em2 = B[(size_t)(j + 2) * NSYM + o];
            em3 = B[(size_t)(j + 3) * NSYM + o];
        }

        // ---- batch-poll this wave's 16 encoded alpha scalars of row t-1 ----
        const int* rb = (const int*)(out + (size_t)(t - 1) * S) + r_l;
        const int* b0 = rb + (w +  0) * 32;
        const int* b1 = rb + (w + 16) * 32;
        const int* b2 = rb + (w + 32) * 32;
        const int* b3 = rb + (w + 48) * 32;
        int e00, e01, e02, e03, e10, e11, e12, e13;
        int e20, e21, e22, e23, e30, e31, e32, e33;
        for (;;) {
            POLL4(e00, e01, e02, e03, b0);
            POLL4(e10, e11, e12, e13, b1);
            POLL4(e20, e21, e22, e23, b2);
            POLL4(e30, e31, e32, e33, b3);
            asm volatile("s_waitcnt vmcnt(0)" ::: "memory");
            const int m0 = (e00 < READY) | (e01 < READY) | (e02 < READY) | (e03 < READY);
            const int m1 = (e10 < READY) | (e11 < READY) | (e12 < READY) | (e13 < READY);
            const int m2 = (e20 < READY) | (e21 < READY) | (e22 < READY) | (e23 < READY);
            const int m3 = (e30 < READY) | (e31 < READY) | (e32 < READY) | (e33 < READY);
            if (!(m0 | m1 | m2 | m3)) break;
        }

        // ---- decode + FMA vs register-resident A ----
        float4 acc = make_float4(0.f, 0.f, 0.f, 0.f);
        int nzacc = 0;
        #define STEP1(E, Q, Ss)                                                \
            { const int d = (E) - READY; nzacc |= d;                           \
              const float af = __int_as_float(d);                              \
              acc.x = fmaf(af, a_reg[Q][Ss].x, acc.x);                         \
              acc.y = fmaf(af, a_reg[Q][Ss].y, acc.y);                         \
              acc.z = fmaf(af, a_reg[Q][Ss].z, acc.z);                         \
              acc.w = fmaf(af, a_reg[Q][Ss].w, acc.w); }
        STEP1(e00,0,0) STEP1(e01,0,1) STEP1(e02,0,2) STEP1(e03,0,3)
        STEP1(e10,1,0) STEP1(e11,1,1) STEP1(e12,1,2) STEP1(e13,1,3)
        STEP1(e20,2,0) STEP1(e21,2,1) STEP1(e22,2,2) STEP1(e23,2,3)
        STEP1(e30,3,0) STEP1(e31,3,1) STEP1(e32,3,2) STEP1(e33,3,3)
        #undef STEP1

        // in-wave reduce over lane bits 3,4,5 (the 8 r_l groups)
        #pragma unroll
        for (int m = 8; m <= 32; m <<= 1) {
            acc.x += __shfl_xor(acc.x, m);
            acc.y += __shfl_xor(acc.y, m);
            acc.z += __shfl_xor(acc.z, m);
            acc.w += __shfl_xor(acc.w, m);
        }
        if (lane < 8) s_wpart[w][lane] = acc;
        const unsigned long long nzm = __ballot(nzacc != 0);
        if (nzm != 0ull && lane == 0) s_nz[t & 3] = 1;   // benign same-value race
        if (tx == 0) s_nz[(t + 2) & 3] = 0;              // prep 2 steps ahead
        __syncthreads();                                 // the ONLY per-step barrier

        if (s_nz[t & 3] == 0) { lastRow = t - 1; break; }   // uniform everywhere

        // ---- wave0: combine 16 wave-partials, emission-multiply, publish ----
        if (tx < 64) {
            const int h = tx >> 3, c = tx & 7;
            float4 p = s_wpart[h][c];
            const float4 q4 = s_wpart[h + 8][c];
            p.x += q4.x; p.y += q4.y; p.z += q4.z; p.w += q4.w;
            #pragma unroll
            for (int m = 8; m <= 32; m <<= 1) {
                p.x += __shfl_xor(p.x, m);
                p.y += __shfl_xor(p.y, m);
                p.z += __shfl_xor(p.z, m);
                p.w += __shfl_xor(p.w, m);
            }
            if (tx < 8) {
                v4i e;
                e.x = __float_as_int(p.x * em0) + READY;
                e.y = __float_as_int(p.y * em1) + READY;
                e.z = __float_as_int(p.z * em2) + READY;
                e.w = __float_as_int(p.w * em3) + READY;
                store_coherent_i4((int*)(out + (size_t)t * S) + b * 32 + tx * 4, e);
            }
        }
        // no bottom barrier: next step's polls gate progress (R7/R8-proven).
    }

    // ---- release the fillers: recurrence traffic is over ----
    if (tx == 0)
        __hip_atomic_store(&flag[NCBLK + 1], 1u, __ATOMIC_RELAXED,
                           __HIP_MEMORY_SCOPE_AGENT);

    // ---- one-time rendezvous: nobody decodes rows still being poll-read ----
    if (tx == 0)
        __hip_atomic_store(&flag[b], 1u, __ATOMIC_RELAXED, __HIP_MEMORY_SCOPE_AGENT);
    if (tx < 64) {
        for (;;) {
            const unsigned f = __hip_atomic_load(&flag[tx], __ATOMIC_RELAXED,
                                                 __HIP_MEMORY_SCOPE_AGENT);
            if (__all(f == 1u)) break;
            __builtin_amdgcn_s_sleep(1);
        }
    }
    __syncthreads();

    // ---- decode own chunks of rows 0..lastRow in place ----
    for (int idx = tx; idx < (lastRow + 1) * 8; idx += NTHR) {
        const int r = idx >> 3, c = idx & 7;
        int* p = (int*)(out + (size_t)r * S) + b * 32 + c * 4;
        v4i e = load_coherent_i4(p);
        e.x -= READY; e.y -= READY; e.z -= READY; e.w -= READY;
        store_coherent_i4(p, e);
    }

    // ---- residue zero-fill: rows lastRow+1 .. FILL_START-1 (fillers own the rest)
    {
        const int zbeg = lastRow + 1;
        const int zend = (FILL_START > zbeg) ? FILL_START : zbeg;
        const size_t beg4 = (size_t)zbeg * (S / 4);
        const size_t end4 = (size_t)zend * (S / 4);
        const v4f z = {0.f, 0.f, 0.f, 0.f};
        v4f* o4 = (v4f*)out;
        for (size_t i = beg4 + (size_t)b * NTHR + tx; i < end4;
             i += (size_t)NCBLK * NTHR)
            __builtin_nontemporal_store(z, &o4[i]);
    }
}

extern "C" void kernel_launch(void* const* d_in, const int* in_sizes, int n_in,
                              void* d_out, int out_size, void* d_ws, size_t ws_size,
                              hipStream_t stream) {
    const int*   obs = (const int*)d_in[0];
    const float* A   = (const float*)d_in[1];
    const float* B   = (const float*)d_in[2];
    const float* pi  = (const float*)d_in[3];
    float* out = (float*)d_out;
    unsigned* flag = (unsigned*)d_ws;

    // d_ws is poisoned before every launch; rendezvous flags + filler
    // done-counter + go-flag must start at 0.
    (void)hipMemsetAsync(d_ws, 0, (size_t)(NCBLK + 2) * sizeof(unsigned), stream);

    hmm_fwd<<<dim3(NBLK), dim3(NTHR), 0, stream>>>(obs, A, B, pi, out, flag);
}